// Round 5
// baseline (623.739 us; speedup 1.0000x reference)
//
#include <hip/hip_runtime.h>
#include <cstdint>

typedef unsigned int u32;
typedef unsigned short u16;

#define N_NODES 100000
#define N_EDGES 3200000
#define F_IN 128
#define DIM 10
#define QB 16            // bf16 elems per padded q row -> 32B, one cache line half
#define HPAD 12          // f32 h2 row stride (48B) for the pool kernel
#define B_GRAPHS 1000
#define NBLK_N 391       // ceil(N/256)
#define RNG 128          // dst nodes per bucket
#define NBKT 782         // ceil(100000/128)
#define CAP 4608         // slots/bucket: mean 4096 + 8 sigma
#define CHUNK 8192       // edges per k_bucket block
#define NBLK_E 391       // ceil(E/CHUNK)
#define ACCS 11          // LDS acc row stride; gcd(11,32)=1 spreads banks

__device__ __forceinline__ u16 f2b(float f) {           // f32 -> bf16 (RNE)
  union { float f; u32 i; } c; c.f = f;
  u32 r = c.i + 0x7FFFu + ((c.i >> 16) & 1u);
  return (u16)(r >> 16);
}
__device__ __forceinline__ float bl(u32 u) {            // low bf16 -> f32
  union { u32 i; float f; } c; c.i = u << 16; return c.f;
}
__device__ __forceinline__ float bh(u32 u) {            // high bf16 -> f32
  union { u32 i; float f; } c; c.i = u & 0xFFFF0000u; return c.f;
}

// p1 = x @ W1[:128,:] (f32, stride 10); q1 = x @ W1[128:,:] (bf16, 32B rows)
__global__ __launch_bounds__(256) void k_gemm1(
    const float* __restrict__ x, const float* __restrict__ W,
    float* __restrict__ p1, u16* __restrict__ q1b)
{
  int i = blockIdx.x * 256 + threadIdx.x;
  if (i >= N_NODES) return;
  const float4* __restrict__ xr = (const float4*)(x + (size_t)i * F_IN);
  float ap[DIM], aq[DIM];
  #pragma unroll
  for (int j = 0; j < DIM; ++j) { ap[j] = 0.f; aq[j] = 0.f; }
  #pragma unroll 4
  for (int k4 = 0; k4 < F_IN / 4; ++k4) {
    float4 v = xr[k4];
    const float* __restrict__ w0 = W + (k4 * 4) * DIM;
    const float* __restrict__ w1 = W + (F_IN + k4 * 4) * DIM;
    #pragma unroll
    for (int j = 0; j < DIM; ++j) {
      ap[j] += v.x * w0[j] + v.y * w0[DIM + j] + v.z * w0[2 * DIM + j] + v.w * w0[3 * DIM + j];
      aq[j] += v.x * w1[j] + v.y * w1[DIM + j] + v.z * w1[2 * DIM + j] + v.w * w1[3 * DIM + j];
    }
  }
  float* pr = p1 + (size_t)i * DIM;
  #pragma unroll
  for (int j = 0; j < DIM; ++j) pr[j] = ap[j];
  u32* qr = (u32*)(q1b + (size_t)i * QB);
  uint4 v0; u32 v1;
  v0.x = (u32)f2b(aq[0]) | ((u32)f2b(aq[1]) << 16);
  v0.y = (u32)f2b(aq[2]) | ((u32)f2b(aq[3]) << 16);
  v0.z = (u32)f2b(aq[4]) | ((u32)f2b(aq[5]) << 16);
  v0.w = (u32)f2b(aq[6]) | ((u32)f2b(aq[7]) << 16);
  v1   = (u32)f2b(aq[8]) | ((u32)f2b(aq[9]) << 16);
  *(uint4*)qr = v0;
  qr[4] = v1;
}

// Bucket edges by dst range: one global atomic per (block,bucket), records
// rank-contiguous per (block,bucket) -> partial write combining.
__global__ __launch_bounds__(256) void k_bucket(
    const int* __restrict__ src, const int* __restrict__ dst,
    u32* __restrict__ gcur, u32* __restrict__ buckets)
{
  __shared__ u32 hcnt[NBKT];
  __shared__ u32 gbase[NBKT];
  int tid = threadIdx.x;
  for (int k = tid; k < NBKT; k += 256) hcnt[k] = 0u;
  __syncthreads();
  int base = blockIdx.x * CHUNK;
  #pragma unroll
  for (int it = 0; it < CHUNK / 256; ++it) {
    int e = base + it * 256 + tid;
    if (e < N_EDGES) atomicAdd(&hcnt[(u32)dst[e] >> 7], 1u);
  }
  __syncthreads();
  for (int k = tid; k < NBKT; k += 256) {
    u32 c = hcnt[k];
    gbase[k] = c ? atomicAdd(&gcur[k], c) : 0u;
    hcnt[k] = 0u;
  }
  __syncthreads();
  #pragma unroll
  for (int it = 0; it < CHUNK / 256; ++it) {
    int e = base + it * 256 + tid;
    if (e < N_EDGES) {
      u32 d = (u32)dst[e];
      u32 bkt = d >> 7;
      u32 ofs = atomicAdd(&hcnt[bkt], 1u);
      u32 p = gbase[bkt] + ofs;
      if (p < CAP)   // statistically impossible; memory-safety only
        buckets[(size_t)bkt * CAP + p] = ((d & 127u) << 17) | (u32)src[e];
    }
  }
}

// Layer 1: one block per bucket; gather bf16 q1 rows (L2-resident 3.2MB array),
// accumulate f32 in LDS; epilogue: h = relu(p1+mean), (p2,q2) = h @ W2.
__global__ __launch_bounds__(256) void k_lay1(
    const u32* __restrict__ gcur, const u32* __restrict__ buckets,
    const float* __restrict__ p1, const u16* __restrict__ q1b,
    const float* __restrict__ W2,
    float* __restrict__ p2, u16* __restrict__ q2b)
{
  __shared__ float acc[RNG * ACCS];
  __shared__ int cnt[RNG];
  __shared__ float w[2 * DIM * DIM];
  int tid = threadIdx.x;
  for (int k = tid; k < RNG * ACCS; k += 256) acc[k] = 0.f;
  if (tid < RNG) cnt[tid] = 0;
  for (int k = tid; k < 2 * DIM * DIM; k += 256) w[k] = W2[k];
  __syncthreads();
  int b = blockIdx.x;
  int n = min((int)gcur[b], CAP);
  const u32* __restrict__ rec = buckets + (size_t)b * CAP;
  for (int r = tid; r < n; r += 256) {
    u32 v = rec[r];
    int s = v & 0x1FFFF;
    int dl = v >> 17;
    const u32* __restrict__ q = (const u32*)(q1b + (size_t)s * QB);
    uint4 A = *(const uint4*)q;
    u32 B5 = q[4];
    float* a = acc + dl * ACCS;
    atomicAdd(&a[0], bl(A.x)); atomicAdd(&a[1], bh(A.x));
    atomicAdd(&a[2], bl(A.y)); atomicAdd(&a[3], bh(A.y));
    atomicAdd(&a[4], bl(A.z)); atomicAdd(&a[5], bh(A.z));
    atomicAdd(&a[6], bl(A.w)); atomicAdd(&a[7], bh(A.w));
    atomicAdd(&a[8], bl(B5));  atomicAdd(&a[9], bh(B5));
    atomicAdd(&cnt[dl], 1);
  }
  __syncthreads();
  if (tid < RNG) {
    int i = b * RNG + tid;
    if (i < N_NODES) {
      float inv = 1.0f / fmaxf((float)cnt[tid], 1.0f);
      const float* __restrict__ pr = p1 + (size_t)i * DIM;
      const float* a = acc + tid * ACCS;
      float h[DIM];
      #pragma unroll
      for (int j = 0; j < DIM; ++j) h[j] = fmaxf(pr[j] + a[j] * inv, 0.0f);
      float aa[DIM], bb[DIM];
      #pragma unroll
      for (int j = 0; j < DIM; ++j) {
        float s0 = 0.f, s1 = 0.f;
        #pragma unroll
        for (int k = 0; k < DIM; ++k) {
          s0 += h[k] * w[k * DIM + j];
          s1 += h[k] * w[(DIM + k) * DIM + j];
        }
        aa[j] = s0; bb[j] = s1;
      }
      float* po = p2 + (size_t)i * DIM;
      #pragma unroll
      for (int j = 0; j < DIM; ++j) po[j] = aa[j];
      u32* qo = (u32*)(q2b + (size_t)i * QB);
      uint4 v0; u32 v1;
      v0.x = (u32)f2b(bb[0]) | ((u32)f2b(bb[1]) << 16);
      v0.y = (u32)f2b(bb[2]) | ((u32)f2b(bb[3]) << 16);
      v0.z = (u32)f2b(bb[4]) | ((u32)f2b(bb[5]) << 16);
      v0.w = (u32)f2b(bb[6]) | ((u32)f2b(bb[7]) << 16);
      v1   = (u32)f2b(bb[8]) | ((u32)f2b(bb[9]) << 16);
      *(uint4*)qo = v0;
      qo[4] = v1;
    }
  }
}

// Layer 2: gather bf16 q2 rows; epilogue h2 = p2 + mean (f32, stride 12).
__global__ __launch_bounds__(256) void k_lay2(
    const u32* __restrict__ gcur, const u32* __restrict__ buckets,
    const float* __restrict__ p2, const u16* __restrict__ q2b,
    float* __restrict__ h2)
{
  __shared__ float acc[RNG * ACCS];
  __shared__ int cnt[RNG];
  int tid = threadIdx.x;
  for (int k = tid; k < RNG * ACCS; k += 256) acc[k] = 0.f;
  if (tid < RNG) cnt[tid] = 0;
  __syncthreads();
  int b = blockIdx.x;
  int n = min((int)gcur[b], CAP);
  const u32* __restrict__ rec = buckets + (size_t)b * CAP;
  for (int r = tid; r < n; r += 256) {
    u32 v = rec[r];
    int s = v & 0x1FFFF;
    int dl = v >> 17;
    const u32* __restrict__ q = (const u32*)(q2b + (size_t)s * QB);
    uint4 A = *(const uint4*)q;
    u32 B5 = q[4];
    float* a = acc + dl * ACCS;
    atomicAdd(&a[0], bl(A.x)); atomicAdd(&a[1], bh(A.x));
    atomicAdd(&a[2], bl(A.y)); atomicAdd(&a[3], bh(A.y));
    atomicAdd(&a[4], bl(A.z)); atomicAdd(&a[5], bh(A.z));
    atomicAdd(&a[6], bl(A.w)); atomicAdd(&a[7], bh(A.w));
    atomicAdd(&a[8], bl(B5));  atomicAdd(&a[9], bh(B5));
    atomicAdd(&cnt[dl], 1);
  }
  __syncthreads();
  if (tid < RNG) {
    int i = b * RNG + tid;
    if (i < N_NODES) {
      float inv = 1.0f / fmaxf((float)cnt[tid], 1.0f);
      const float* __restrict__ pr = p2 + (size_t)i * DIM;
      const float* a = acc + tid * ACCS;
      float* ho = h2 + (size_t)i * HPAD;
      #pragma unroll
      for (int j = 0; j < DIM; ++j) ho[j] = pr[j] + a[j] * inv;
    }
  }
}

// one wave per graph: binary-search node range in sorted batch, mean-pool,
// dot with Wfc, sigmoid -> out[b]. Zero atomics.
__global__ __launch_bounds__(64) void k_pool(
    const float* __restrict__ h2, const int* __restrict__ batch,
    const float* __restrict__ Wfc, float* __restrict__ out)
{
  int b = blockIdx.x;
  int lo = 0, hi = N_NODES;
  while (lo < hi) { int m = (lo + hi) >> 1; if (batch[m] < b) lo = m + 1; else hi = m; }
  int start = lo;
  hi = N_NODES;
  while (lo < hi) { int m = (lo + hi) >> 1; if (batch[m] < b + 1) lo = m + 1; else hi = m; }
  int end = lo;
  float sum[DIM];
  #pragma unroll
  for (int j = 0; j < DIM; ++j) sum[j] = 0.f;
  for (int r = start + (int)threadIdx.x; r < end; r += 64) {
    const float4* __restrict__ p = (const float4*)(h2 + (size_t)r * HPAD);
    float4 r0 = p[0], r1 = p[1];
    float2 r2 = *(const float2*)(h2 + (size_t)r * HPAD + 8);
    sum[0] += r0.x; sum[1] += r0.y; sum[2] += r0.z; sum[3] += r0.w;
    sum[4] += r1.x; sum[5] += r1.y; sum[6] += r1.z; sum[7] += r1.w;
    sum[8] += r2.x; sum[9] += r2.y;
  }
  #pragma unroll
  for (int m = 1; m < 64; m <<= 1) {
    #pragma unroll
    for (int j = 0; j < DIM; ++j) sum[j] += __shfl_xor(sum[j], m, 64);
  }
  if (threadIdx.x == 0) {
    float inv = 1.0f / fmaxf((float)(end - start), 1.0f);
    float acc = 0.f;
    #pragma unroll
    for (int j = 0; j < DIM; ++j) acc += sum[j] * inv * Wfc[j];
    out[b] = 1.0f / (1.0f + expf(-acc));
  }
}

extern "C" void kernel_launch(void* const* d_in, const int* in_sizes, int n_in,
                              void* d_out, int out_size, void* d_ws, size_t ws_size,
                              hipStream_t stream)
{
  const float* x     = (const float*)d_in[0];
  const int*   ei    = (const int*)d_in[1];
  const int*   batch = (const int*)d_in[2];
  const float* W1    = (const float*)d_in[3];
  const float* W2    = (const float*)d_in[4];
  const float* Wfc   = (const float*)d_in[5];
  float* out = (float*)d_out;

  const int* src = ei;            // edge_index[0]
  const int* dst = ei + N_EDGES;  // edge_index[1]

  // ---- workspace layout (offsets all 32B-aligned where vec-loaded) ----
  u32* gcur    = (u32*)d_ws;                        // 782 used, pad to 1024 (zeroed)
  u32* buckets = gcur + 1024;                       // NBKT*CAP = 3,603,456 (14.4MB)
  u16* q1b = (u16*)(buckets + (size_t)NBKT * CAP);  // N*16 bf16 = 3.2MB (L2-resident)
  u16* q2b = q1b + (size_t)N_NODES * QB;            // 3.2MB
  float* p1 = (float*)(q2b + (size_t)N_NODES * QB); // N*10 f32
  float* p2 = p1 + (size_t)N_NODES * DIM;           // N*10 f32
  float* h2 = p2 + (size_t)N_NODES * DIM;           // N*12 f32

  hipMemsetAsync(gcur, 0, 1024 * sizeof(u32), stream);

  k_gemm1 <<<NBLK_N, 256, 0, stream>>>(x, W1, p1, q1b);
  k_bucket<<<NBLK_E, 256, 0, stream>>>(src, dst, gcur, buckets);
  k_lay1  <<<NBKT, 256, 0, stream>>>(gcur, buckets, p1, q1b, W2, p2, q2b);
  k_lay2  <<<NBKT, 256, 0, stream>>>(gcur, buckets, p2, q2b, h2);
  k_pool  <<<B_GRAPHS, 64, 0, stream>>>(h2, batch, Wfc, out);
}

// Round 6
// 588.340 us; speedup vs baseline: 1.0602x; 1.0602x over previous
//
#include <hip/hip_runtime.h>
#include <cstdint>

typedef unsigned int u32;
typedef unsigned short u16;

#define N_NODES 100000
#define N_EDGES 3200000
#define F_IN 128
#define DIM 10
#define QB 16            // bf16 elems per padded q row -> 32B
#define HPAD 12          // f32 h2 row stride (48B) for the pool kernel
#define B_GRAPHS 1000
#define NBLK_N 391       // ceil(N/256)
#define RNG 64           // dst nodes per bucket (was 128; more blocks = occupancy)
#define NBKT 1563        // ceil(100000/64)
#define CAP 2560         // slots/bucket: mean 2048 + 11 sigma (sigma~45)
#define CHUNK 8192       // edges per k_bucket block
#define NBLK_E 391       // ceil(E/CHUNK)
#define ACCS 11          // LDS acc row stride; gcd(11,32)=1 spreads banks

__device__ __forceinline__ u16 f2b(float f) {           // f32 -> bf16 (RNE)
  union { float f; u32 i; } c; c.f = f;
  u32 r = c.i + 0x7FFFu + ((c.i >> 16) & 1u);
  return (u16)(r >> 16);
}
__device__ __forceinline__ float bl(u32 u) {            // low bf16 -> f32
  union { u32 i; float f; } c; c.i = u << 16; return c.f;
}
__device__ __forceinline__ float bh(u32 u) {            // high bf16 -> f32
  union { u32 i; float f; } c; c.i = u & 0xFFFF0000u; return c.f;
}

// p1 = x @ W1[:128,:] (f32, stride 10); q1 = x @ W1[128:,:] (bf16, 32B rows)
__global__ __launch_bounds__(256) void k_gemm1(
    const float* __restrict__ x, const float* __restrict__ W,
    float* __restrict__ p1, u16* __restrict__ q1b)
{
  int i = blockIdx.x * 256 + threadIdx.x;
  if (i >= N_NODES) return;
  const float4* __restrict__ xr = (const float4*)(x + (size_t)i * F_IN);
  float ap[DIM], aq[DIM];
  #pragma unroll
  for (int j = 0; j < DIM; ++j) { ap[j] = 0.f; aq[j] = 0.f; }
  #pragma unroll 4
  for (int k4 = 0; k4 < F_IN / 4; ++k4) {
    float4 v = xr[k4];
    const float* __restrict__ w0 = W + (k4 * 4) * DIM;
    const float* __restrict__ w1 = W + (F_IN + k4 * 4) * DIM;
    #pragma unroll
    for (int j = 0; j < DIM; ++j) {
      ap[j] += v.x * w0[j] + v.y * w0[DIM + j] + v.z * w0[2 * DIM + j] + v.w * w0[3 * DIM + j];
      aq[j] += v.x * w1[j] + v.y * w1[DIM + j] + v.z * w1[2 * DIM + j] + v.w * w1[3 * DIM + j];
    }
  }
  float* pr = p1 + (size_t)i * DIM;
  #pragma unroll
  for (int j = 0; j < DIM; ++j) pr[j] = ap[j];
  u32* qr = (u32*)(q1b + (size_t)i * QB);
  uint4 v0; u32 v1;
  v0.x = (u32)f2b(aq[0]) | ((u32)f2b(aq[1]) << 16);
  v0.y = (u32)f2b(aq[2]) | ((u32)f2b(aq[3]) << 16);
  v0.z = (u32)f2b(aq[4]) | ((u32)f2b(aq[5]) << 16);
  v0.w = (u32)f2b(aq[6]) | ((u32)f2b(aq[7]) << 16);
  v1   = (u32)f2b(aq[8]) | ((u32)f2b(aq[9]) << 16);
  *(uint4*)qr = v0;
  qr[4] = v1;
}

// Bucket edges by dst range: one global atomic per (block,bucket), records
// rank-contiguous per (block,bucket).
__global__ __launch_bounds__(256) void k_bucket(
    const int* __restrict__ src, const int* __restrict__ dst,
    u32* __restrict__ gcur, u32* __restrict__ buckets)
{
  __shared__ u32 hcnt[NBKT];
  __shared__ u32 gbase[NBKT];
  int tid = threadIdx.x;
  for (int k = tid; k < NBKT; k += 256) hcnt[k] = 0u;
  __syncthreads();
  int base = blockIdx.x * CHUNK;
  #pragma unroll
  for (int it = 0; it < CHUNK / 256; ++it) {
    int e = base + it * 256 + tid;
    if (e < N_EDGES) atomicAdd(&hcnt[(u32)dst[e] >> 6], 1u);
  }
  __syncthreads();
  for (int k = tid; k < NBKT; k += 256) {
    u32 c = hcnt[k];
    gbase[k] = c ? atomicAdd(&gcur[k], c) : 0u;
    hcnt[k] = 0u;
  }
  __syncthreads();
  #pragma unroll
  for (int it = 0; it < CHUNK / 256; ++it) {
    int e = base + it * 256 + tid;
    if (e < N_EDGES) {
      u32 d = (u32)dst[e];
      u32 bkt = d >> 6;
      u32 ofs = atomicAdd(&hcnt[bkt], 1u);
      u32 p = gbase[bkt] + ofs;
      if (p < CAP)   // statistically impossible; memory-safety only
        buckets[(size_t)bkt * CAP + p] = ((d & 63u) << 17) | (u32)src[e];
    }
  }
}

// Layer 1: one block per bucket (64 dst nodes); gather bf16 q1 rows,
// f32 LDS-atomic accumulate (2-way unrolled for MLP); epilogue:
// h = relu(p1+mean), (p2,q2) = h @ W2.
__global__ __launch_bounds__(256) void k_lay1(
    const u32* __restrict__ gcur, const u32* __restrict__ buckets,
    const float* __restrict__ p1, const u16* __restrict__ q1b,
    const float* __restrict__ W2,
    float* __restrict__ p2, u16* __restrict__ q2b)
{
  __shared__ float acc[RNG * ACCS];
  __shared__ int cnt[RNG];
  __shared__ float w[2 * DIM * DIM];
  int tid = threadIdx.x;
  for (int k = tid; k < RNG * ACCS; k += 256) acc[k] = 0.f;
  if (tid < RNG) cnt[tid] = 0;
  for (int k = tid; k < 2 * DIM * DIM; k += 256) w[k] = W2[k];
  __syncthreads();
  int b = blockIdx.x;
  int n = min((int)gcur[b], CAP);
  const u32* __restrict__ rec = buckets + (size_t)b * CAP;
  for (int r = tid; r < n; r += 512) {
    int rr = r + 256;
    bool two = rr < n;
    u32 v0 = rec[r];
    u32 v1 = two ? rec[rr] : v0;
    int s0 = v0 & 0x1FFFF, dl0 = v0 >> 17;
    int s1 = v1 & 0x1FFFF, dl1 = v1 >> 17;
    const u32* __restrict__ q0 = (const u32*)(q1b + (size_t)s0 * QB);
    const u32* __restrict__ q1 = (const u32*)(q1b + (size_t)s1 * QB);
    uint4 A0 = *(const uint4*)q0; u32 B0 = q0[4];
    uint4 A1 = *(const uint4*)q1; u32 B1 = q1[4];
    float* a0 = acc + dl0 * ACCS;
    atomicAdd(&a0[0], bl(A0.x)); atomicAdd(&a0[1], bh(A0.x));
    atomicAdd(&a0[2], bl(A0.y)); atomicAdd(&a0[3], bh(A0.y));
    atomicAdd(&a0[4], bl(A0.z)); atomicAdd(&a0[5], bh(A0.z));
    atomicAdd(&a0[6], bl(A0.w)); atomicAdd(&a0[7], bh(A0.w));
    atomicAdd(&a0[8], bl(B0));   atomicAdd(&a0[9], bh(B0));
    atomicAdd(&cnt[dl0], 1);
    if (two) {
      float* a1 = acc + dl1 * ACCS;
      atomicAdd(&a1[0], bl(A1.x)); atomicAdd(&a1[1], bh(A1.x));
      atomicAdd(&a1[2], bl(A1.y)); atomicAdd(&a1[3], bh(A1.y));
      atomicAdd(&a1[4], bl(A1.z)); atomicAdd(&a1[5], bh(A1.z));
      atomicAdd(&a1[6], bl(A1.w)); atomicAdd(&a1[7], bh(A1.w));
      atomicAdd(&a1[8], bl(B1));   atomicAdd(&a1[9], bh(B1));
      atomicAdd(&cnt[dl1], 1);
    }
  }
  __syncthreads();
  if (tid < RNG) {
    int i = b * RNG + tid;
    if (i < N_NODES) {
      float inv = 1.0f / fmaxf((float)cnt[tid], 1.0f);
      const float* __restrict__ pr = p1 + (size_t)i * DIM;
      const float* a = acc + tid * ACCS;
      float h[DIM];
      #pragma unroll
      for (int j = 0; j < DIM; ++j) h[j] = fmaxf(pr[j] + a[j] * inv, 0.0f);
      float aa[DIM], bb[DIM];
      #pragma unroll
      for (int j = 0; j < DIM; ++j) {
        float s0 = 0.f, s1 = 0.f;
        #pragma unroll
        for (int k = 0; k < DIM; ++k) {
          s0 += h[k] * w[k * DIM + j];
          s1 += h[k] * w[(DIM + k) * DIM + j];
        }
        aa[j] = s0; bb[j] = s1;
      }
      float* po = p2 + (size_t)i * DIM;
      #pragma unroll
      for (int j = 0; j < DIM; ++j) po[j] = aa[j];
      u32* qo = (u32*)(q2b + (size_t)i * QB);
      uint4 v0; u32 v1;
      v0.x = (u32)f2b(bb[0]) | ((u32)f2b(bb[1]) << 16);
      v0.y = (u32)f2b(bb[2]) | ((u32)f2b(bb[3]) << 16);
      v0.z = (u32)f2b(bb[4]) | ((u32)f2b(bb[5]) << 16);
      v0.w = (u32)f2b(bb[6]) | ((u32)f2b(bb[7]) << 16);
      v1   = (u32)f2b(bb[8]) | ((u32)f2b(bb[9]) << 16);
      *(uint4*)qo = v0;
      qo[4] = v1;
    }
  }
}

// Layer 2: same gather on q2b; epilogue h2 = p2 + mean (f32, stride 12).
__global__ __launch_bounds__(256) void k_lay2(
    const u32* __restrict__ gcur, const u32* __restrict__ buckets,
    const float* __restrict__ p2, const u16* __restrict__ q2b,
    float* __restrict__ h2)
{
  __shared__ float acc[RNG * ACCS];
  __shared__ int cnt[RNG];
  int tid = threadIdx.x;
  for (int k = tid; k < RNG * ACCS; k += 256) acc[k] = 0.f;
  if (tid < RNG) cnt[tid] = 0;
  __syncthreads();
  int b = blockIdx.x;
  int n = min((int)gcur[b], CAP);
  const u32* __restrict__ rec = buckets + (size_t)b * CAP;
  for (int r = tid; r < n; r += 512) {
    int rr = r + 256;
    bool two = rr < n;
    u32 v0 = rec[r];
    u32 v1 = two ? rec[rr] : v0;
    int s0 = v0 & 0x1FFFF, dl0 = v0 >> 17;
    int s1 = v1 & 0x1FFFF, dl1 = v1 >> 17;
    const u32* __restrict__ q0 = (const u32*)(q2b + (size_t)s0 * QB);
    const u32* __restrict__ q1 = (const u32*)(q2b + (size_t)s1 * QB);
    uint4 A0 = *(const uint4*)q0; u32 B0 = q0[4];
    uint4 A1 = *(const uint4*)q1; u32 B1 = q1[4];
    float* a0 = acc + dl0 * ACCS;
    atomicAdd(&a0[0], bl(A0.x)); atomicAdd(&a0[1], bh(A0.x));
    atomicAdd(&a0[2], bl(A0.y)); atomicAdd(&a0[3], bh(A0.y));
    atomicAdd(&a0[4], bl(A0.z)); atomicAdd(&a0[5], bh(A0.z));
    atomicAdd(&a0[6], bl(A0.w)); atomicAdd(&a0[7], bh(A0.w));
    atomicAdd(&a0[8], bl(B0));   atomicAdd(&a0[9], bh(B0));
    atomicAdd(&cnt[dl0], 1);
    if (two) {
      float* a1 = acc + dl1 * ACCS;
      atomicAdd(&a1[0], bl(A1.x)); atomicAdd(&a1[1], bh(A1.x));
      atomicAdd(&a1[2], bl(A1.y)); atomicAdd(&a1[3], bh(A1.y));
      atomicAdd(&a1[4], bl(A1.z)); atomicAdd(&a1[5], bh(A1.z));
      atomicAdd(&a1[6], bl(A1.w)); atomicAdd(&a1[7], bh(A1.w));
      atomicAdd(&a1[8], bl(B1));   atomicAdd(&a1[9], bh(B1));
      atomicAdd(&cnt[dl1], 1);
    }
  }
  __syncthreads();
  if (tid < RNG) {
    int i = b * RNG + tid;
    if (i < N_NODES) {
      float inv = 1.0f / fmaxf((float)cnt[tid], 1.0f);
      const float* __restrict__ pr = p2 + (size_t)i * DIM;
      const float* a = acc + tid * ACCS;
      float* ho = h2 + (size_t)i * HPAD;
      #pragma unroll
      for (int j = 0; j < DIM; ++j) ho[j] = pr[j] + a[j] * inv;
    }
  }
}

// one wave per graph: binary-search node range in sorted batch, mean-pool,
// dot with Wfc, sigmoid -> out[b]. Zero atomics.
__global__ __launch_bounds__(64) void k_pool(
    const float* __restrict__ h2, const int* __restrict__ batch,
    const float* __restrict__ Wfc, float* __restrict__ out)
{
  int b = blockIdx.x;
  int lo = 0, hi = N_NODES;
  while (lo < hi) { int m = (lo + hi) >> 1; if (batch[m] < b) lo = m + 1; else hi = m; }
  int start = lo;
  hi = N_NODES;
  while (lo < hi) { int m = (lo + hi) >> 1; if (batch[m] < b + 1) lo = m + 1; else hi = m; }
  int end = lo;
  float sum[DIM];
  #pragma unroll
  for (int j = 0; j < DIM; ++j) sum[j] = 0.f;
  for (int r = start + (int)threadIdx.x; r < end; r += 64) {
    const float4* __restrict__ p = (const float4*)(h2 + (size_t)r * HPAD);
    float4 r0 = p[0], r1 = p[1];
    float2 r2 = *(const float2*)(h2 + (size_t)r * HPAD + 8);
    sum[0] += r0.x; sum[1] += r0.y; sum[2] += r0.z; sum[3] += r0.w;
    sum[4] += r1.x; sum[5] += r1.y; sum[6] += r1.z; sum[7] += r1.w;
    sum[8] += r2.x; sum[9] += r2.y;
  }
  #pragma unroll
  for (int m = 1; m < 64; m <<= 1) {
    #pragma unroll
    for (int j = 0; j < DIM; ++j) sum[j] += __shfl_xor(sum[j], m, 64);
  }
  if (threadIdx.x == 0) {
    float inv = 1.0f / fmaxf((float)(end - start), 1.0f);
    float acc = 0.f;
    #pragma unroll
    for (int j = 0; j < DIM; ++j) acc += sum[j] * inv * Wfc[j];
    out[b] = 1.0f / (1.0f + expf(-acc));
  }
}

extern "C" void kernel_launch(void* const* d_in, const int* in_sizes, int n_in,
                              void* d_out, int out_size, void* d_ws, size_t ws_size,
                              hipStream_t stream)
{
  const float* x     = (const float*)d_in[0];
  const int*   ei    = (const int*)d_in[1];
  const int*   batch = (const int*)d_in[2];
  const float* W1    = (const float*)d_in[3];
  const float* W2    = (const float*)d_in[4];
  const float* Wfc   = (const float*)d_in[5];
  float* out = (float*)d_out;

  const int* src = ei;            // edge_index[0]
  const int* dst = ei + N_EDGES;  // edge_index[1]

  // ---- workspace layout (~36 MB) ----
  u32* gcur    = (u32*)d_ws;                        // 1563 used, pad to 2048 (zeroed)
  u32* buckets = gcur + 2048;                       // NBKT*CAP = 4,001,280 (16MB)
  u16* q1b = (u16*)(buckets + (size_t)NBKT * CAP);  // N*16 bf16 = 3.2MB
  u16* q2b = q1b + (size_t)N_NODES * QB;            // 3.2MB
  float* p1 = (float*)(q2b + (size_t)N_NODES * QB); // N*10 f32 (4MB)
  float* p2 = p1 + (size_t)N_NODES * DIM;           // 4MB
  float* h2 = p2 + (size_t)N_NODES * DIM;           // N*12 f32 (4.8MB)

  hipMemsetAsync(gcur, 0, 2048 * sizeof(u32), stream);

  k_gemm1 <<<NBLK_N, 256, 0, stream>>>(x, W1, p1, q1b);
  k_bucket<<<NBLK_E, 256, 0, stream>>>(src, dst, gcur, buckets);
  k_lay1  <<<NBKT, 256, 0, stream>>>(gcur, buckets, p1, q1b, W2, p2, q2b);
  k_lay2  <<<NBKT, 256, 0, stream>>>(gcur, buckets, p2, q2b, h2);
  k_pool  <<<B_GRAPHS, 64, 0, stream>>>(h2, batch, Wfc, out);
}

// Round 7
// 282.719 us; speedup vs baseline: 2.2062x; 2.0810x over previous
//
#include <hip/hip_runtime.h>
#include <cstdint>

typedef unsigned int u32;
typedef unsigned short u16;

#define N_NODES 100000
#define N_EDGES 3200000
#define F_IN 128
#define DIM 10
#define QB 16            // bf16 elems per padded q row -> 32B
#define HPAD 12          // f32 h2 row stride (48B) for the pool kernel
#define B_GRAPHS 1000
#define NBLK_N 391       // ceil(N/256)
#define RNG 64           // dst nodes per bucket
#define NBKT 1563        // ceil(100000/64)
#define CAP 2560         // slots/bucket: mean 2048 + 11 sigma (sigma~45)
#define CHUNK 8192       // edges per k_bucket block
#define NBLK_E 391       // ceil(E/CHUNK)
#define GSTRIDE 16       // gcur padded: one 64B line per bucket cursor

__device__ __forceinline__ u16 f2b(float f) {           // f32 -> bf16 (RNE)
  union { float f; u32 i; } c; c.f = f;
  u32 r = c.i + 0x7FFFu + ((c.i >> 16) & 1u);
  return (u16)(r >> 16);
}
__device__ __forceinline__ float bl(u32 u) {            // low bf16 -> f32
  union { u32 i; float f; } c; c.i = u << 16; return c.f;
}
__device__ __forceinline__ float bh(u32 u) {            // high bf16 -> f32
  union { u32 i; float f; } c; c.i = u & 0xFFFF0000u; return c.f;
}

// p1 = x @ W1[:128,:] (f32, stride 10); q1 = x @ W1[128:,:] (bf16, 32B rows)
__global__ __launch_bounds__(256) void k_gemm1(
    const float* __restrict__ x, const float* __restrict__ W,
    float* __restrict__ p1, u16* __restrict__ q1b)
{
  int i = blockIdx.x * 256 + threadIdx.x;
  if (i >= N_NODES) return;
  const float4* __restrict__ xr = (const float4*)(x + (size_t)i * F_IN);
  float ap[DIM], aq[DIM];
  #pragma unroll
  for (int j = 0; j < DIM; ++j) { ap[j] = 0.f; aq[j] = 0.f; }
  #pragma unroll 4
  for (int k4 = 0; k4 < F_IN / 4; ++k4) {
    float4 v = xr[k4];
    const float* __restrict__ w0 = W + (k4 * 4) * DIM;
    const float* __restrict__ w1 = W + (F_IN + k4 * 4) * DIM;
    #pragma unroll
    for (int j = 0; j < DIM; ++j) {
      ap[j] += v.x * w0[j] + v.y * w0[DIM + j] + v.z * w0[2 * DIM + j] + v.w * w0[3 * DIM + j];
      aq[j] += v.x * w1[j] + v.y * w1[DIM + j] + v.z * w1[2 * DIM + j] + v.w * w1[3 * DIM + j];
    }
  }
  float* pr = p1 + (size_t)i * DIM;
  #pragma unroll
  for (int j = 0; j < DIM; ++j) pr[j] = ap[j];
  u32* qr = (u32*)(q1b + (size_t)i * QB);
  uint4 v0; u32 v1;
  v0.x = (u32)f2b(aq[0]) | ((u32)f2b(aq[1]) << 16);
  v0.y = (u32)f2b(aq[2]) | ((u32)f2b(aq[3]) << 16);
  v0.z = (u32)f2b(aq[4]) | ((u32)f2b(aq[5]) << 16);
  v0.w = (u32)f2b(aq[6]) | ((u32)f2b(aq[7]) << 16);
  v1   = (u32)f2b(aq[8]) | ((u32)f2b(aq[9]) << 16);
  *(uint4*)qr = v0;
  qr[4] = v1;
}

// Bucket edges by dst range: one global atomic per (block,bucket), cursors
// padded to one cache line each (cross-XCD contention), records
// rank-contiguous per (block,bucket).
__global__ __launch_bounds__(256) void k_bucket(
    const int* __restrict__ src, const int* __restrict__ dst,
    u32* __restrict__ gcur, u32* __restrict__ buckets)
{
  __shared__ u32 hcnt[NBKT];
  __shared__ u32 gbase[NBKT];
  int tid = threadIdx.x;
  for (int k = tid; k < NBKT; k += 256) hcnt[k] = 0u;
  __syncthreads();
  int base = blockIdx.x * CHUNK;
  #pragma unroll
  for (int it = 0; it < CHUNK / 256; ++it) {
    int e = base + it * 256 + tid;
    if (e < N_EDGES) atomicAdd(&hcnt[(u32)dst[e] >> 6], 1u);
  }
  __syncthreads();
  for (int k = tid; k < NBKT; k += 256) {
    u32 c = hcnt[k];
    gbase[k] = c ? atomicAdd(&gcur[k * GSTRIDE], c) : 0u;
    hcnt[k] = 0u;
  }
  __syncthreads();
  #pragma unroll
  for (int it = 0; it < CHUNK / 256; ++it) {
    int e = base + it * 256 + tid;
    if (e < N_EDGES) {
      u32 d = (u32)dst[e];
      u32 bkt = d >> 6;
      u32 ofs = atomicAdd(&hcnt[bkt], 1u);
      u32 p = gbase[bkt] + ofs;
      if (p < CAP)   // statistically impossible; memory-safety only
        buckets[(size_t)bkt * CAP + p] = ((d & 63u) << 17) | (u32)src[e];
    }
  }
}

// Shared gather machinery: counting-sort records by dl in LDS, then 4 lanes
// per node reduce the contiguous segment in registers (no f32 atomics).
// sums -> lane (tid&3)==0 holds the per-node aggregate; returns seg length.
#define SORT_AND_GATHER(QSRC)                                                 \
  int tid = threadIdx.x;                                                      \
  __shared__ u32 lrec[CAP];                                                   \
  __shared__ u32 srt[CAP];                                                    \
  __shared__ u32 hist[RNG];                                                   \
  __shared__ u32 segst[RNG + 1];                                              \
  __shared__ u32 rank[RNG];                                                   \
  if (tid < RNG) { hist[tid] = 0u; rank[tid] = 0u; }                          \
  __syncthreads();                                                            \
  int b = blockIdx.x;                                                         \
  int n = min((int)gcur[b * GSTRIDE], CAP);                                   \
  const u32* __restrict__ rec = buckets + (size_t)b * CAP;                    \
  for (int r = tid; r < n; r += 256) {                                        \
    u32 v = rec[r];                                                           \
    lrec[r] = v;                                                              \
    atomicAdd(&hist[v >> 17], 1u);                                            \
  }                                                                           \
  __syncthreads();                                                            \
  if (tid < RNG) {                                                            \
    u32 h = hist[tid];                                                        \
    u32 v = h;                                                                \
    for (int off = 1; off < RNG; off <<= 1) {                                 \
      u32 t = __shfl_up(v, off, 64);                                          \
      if (tid >= off) v += t;                                                 \
    }                                                                         \
    segst[tid] = v - h;                                                       \
    if (tid == RNG - 1) segst[RNG] = v;                                       \
  }                                                                           \
  __syncthreads();                                                            \
  for (int r = tid; r < n; r += 256) {                                        \
    u32 v = lrec[r];                                                          \
    u32 dl = v >> 17;                                                         \
    u32 pos = segst[dl] + atomicAdd(&rank[dl], 1u);                           \
    srt[pos] = v & 0x1FFFFu;                                                  \
  }                                                                           \
  __syncthreads();                                                            \
  int g = tid >> 2;                                                           \
  int l = tid & 3;                                                            \
  int st = (int)segst[g], en = (int)segst[g + 1];                             \
  float s[DIM];                                                               \
  _Pragma("unroll")                                                           \
  for (int j = 0; j < DIM; ++j) s[j] = 0.f;                                   \
  int k = st + l;                                                             \
  for (; k + 4 < en; k += 8) {                                                \
    int s0 = (int)srt[k], s1 = (int)srt[k + 4];                               \
    const u32* __restrict__ q0 = (const u32*)(QSRC + (size_t)s0 * QB);        \
    const u32* __restrict__ q1 = (const u32*)(QSRC + (size_t)s1 * QB);        \
    uint4 A0 = *(const uint4*)q0; u32 B0 = q0[4];                             \
    uint4 A1 = *(const uint4*)q1; u32 B1 = q1[4];                             \
    s[0] += bl(A0.x) + bl(A1.x); s[1] += bh(A0.x) + bh(A1.x);                 \
    s[2] += bl(A0.y) + bl(A1.y); s[3] += bh(A0.y) + bh(A1.y);                 \
    s[4] += bl(A0.z) + bl(A1.z); s[5] += bh(A0.z) + bh(A1.z);                 \
    s[6] += bl(A0.w) + bl(A1.w); s[7] += bh(A0.w) + bh(A1.w);                 \
    s[8] += bl(B0) + bl(B1);     s[9] += bh(B0) + bh(B1);                     \
  }                                                                           \
  if (k < en) {                                                               \
    int s0 = (int)srt[k];                                                     \
    const u32* __restrict__ q0 = (const u32*)(QSRC + (size_t)s0 * QB);        \
    uint4 A0 = *(const uint4*)q0; u32 B0 = q0[4];                             \
    s[0] += bl(A0.x); s[1] += bh(A0.x);                                       \
    s[2] += bl(A0.y); s[3] += bh(A0.y);                                       \
    s[4] += bl(A0.z); s[5] += bh(A0.z);                                       \
    s[6] += bl(A0.w); s[7] += bh(A0.w);                                       \
    s[8] += bl(B0);   s[9] += bh(B0);                                         \
  }                                                                           \
  _Pragma("unroll")                                                           \
  for (int m = 1; m < 4; m <<= 1) {                                           \
    _Pragma("unroll")                                                         \
    for (int j = 0; j < DIM; ++j) s[j] += __shfl_xor(s[j], m, 4);             \
  }

// Layer 1: sorted gather + epilogue h = relu(p1+mean), (p2,q2) = h @ W2.
__global__ __launch_bounds__(256) void k_lay1(
    const u32* __restrict__ gcur, const u32* __restrict__ buckets,
    const float* __restrict__ p1, const u16* __restrict__ q1b,
    const float* __restrict__ W2,
    float* __restrict__ p2, u16* __restrict__ q2b)
{
  __shared__ float w[2 * DIM * DIM];
  for (int t = threadIdx.x; t < 2 * DIM * DIM; t += 256) w[t] = W2[t];
  SORT_AND_GATHER(q1b)
  if (l == 0) {
    int i = b * RNG + g;
    if (i < N_NODES) {
      float inv = 1.0f / fmaxf((float)(en - st), 1.0f);
      const float* __restrict__ pr = p1 + (size_t)i * DIM;
      float h[DIM];
      #pragma unroll
      for (int j = 0; j < DIM; ++j) h[j] = fmaxf(pr[j] + s[j] * inv, 0.0f);
      float aa[DIM], bb[DIM];
      #pragma unroll
      for (int j = 0; j < DIM; ++j) {
        float t0 = 0.f, t1 = 0.f;
        #pragma unroll
        for (int kk = 0; kk < DIM; ++kk) {
          t0 += h[kk] * w[kk * DIM + j];
          t1 += h[kk] * w[(DIM + kk) * DIM + j];
        }
        aa[j] = t0; bb[j] = t1;
      }
      float* po = p2 + (size_t)i * DIM;
      #pragma unroll
      for (int j = 0; j < DIM; ++j) po[j] = aa[j];
      u32* qo = (u32*)(q2b + (size_t)i * QB);
      uint4 v0; u32 v1;
      v0.x = (u32)f2b(bb[0]) | ((u32)f2b(bb[1]) << 16);
      v0.y = (u32)f2b(bb[2]) | ((u32)f2b(bb[3]) << 16);
      v0.z = (u32)f2b(bb[4]) | ((u32)f2b(bb[5]) << 16);
      v0.w = (u32)f2b(bb[6]) | ((u32)f2b(bb[7]) << 16);
      v1   = (u32)f2b(bb[8]) | ((u32)f2b(bb[9]) << 16);
      *(uint4*)qo = v0;
      qo[4] = v1;
    }
  }
}

// Layer 2: sorted gather + epilogue h2 = p2 + mean (f32, stride 12).
__global__ __launch_bounds__(256) void k_lay2(
    const u32* __restrict__ gcur, const u32* __restrict__ buckets,
    const float* __restrict__ p2, const u16* __restrict__ q2b,
    float* __restrict__ h2)
{
  SORT_AND_GATHER(q2b)
  if (l == 0) {
    int i = b * RNG + g;
    if (i < N_NODES) {
      float inv = 1.0f / fmaxf((float)(en - st), 1.0f);
      const float* __restrict__ pr = p2 + (size_t)i * DIM;
      float* ho = h2 + (size_t)i * HPAD;
      #pragma unroll
      for (int j = 0; j < DIM; ++j) ho[j] = pr[j] + s[j] * inv;
    }
  }
}

// one wave per graph: binary-search node range in sorted batch, mean-pool,
// dot with Wfc, sigmoid -> out[b]. Zero atomics.
__global__ __launch_bounds__(64) void k_pool(
    const float* __restrict__ h2, const int* __restrict__ batch,
    const float* __restrict__ Wfc, float* __restrict__ out)
{
  int b = blockIdx.x;
  int lo = 0, hi = N_NODES;
  while (lo < hi) { int m = (lo + hi) >> 1; if (batch[m] < b) lo = m + 1; else hi = m; }
  int start = lo;
  hi = N_NODES;
  while (lo < hi) { int m = (lo + hi) >> 1; if (batch[m] < b + 1) lo = m + 1; else hi = m; }
  int end = lo;
  float sum[DIM];
  #pragma unroll
  for (int j = 0; j < DIM; ++j) sum[j] = 0.f;
  for (int r = start + (int)threadIdx.x; r < end; r += 64) {
    const float4* __restrict__ p = (const float4*)(h2 + (size_t)r * HPAD);
    float4 r0 = p[0], r1 = p[1];
    float2 r2 = *(const float2*)(h2 + (size_t)r * HPAD + 8);
    sum[0] += r0.x; sum[1] += r0.y; sum[2] += r0.z; sum[3] += r0.w;
    sum[4] += r1.x; sum[5] += r1.y; sum[6] += r1.z; sum[7] += r1.w;
    sum[8] += r2.x; sum[9] += r2.y;
  }
  #pragma unroll
  for (int m = 1; m < 64; m <<= 1) {
    #pragma unroll
    for (int j = 0; j < DIM; ++j) sum[j] += __shfl_xor(sum[j], m, 64);
  }
  if (threadIdx.x == 0) {
    float inv = 1.0f / fmaxf((float)(end - start), 1.0f);
    float acc = 0.f;
    #pragma unroll
    for (int j = 0; j < DIM; ++j) acc += sum[j] * inv * Wfc[j];
    out[b] = 1.0f / (1.0f + expf(-acc));
  }
}

extern "C" void kernel_launch(void* const* d_in, const int* in_sizes, int n_in,
                              void* d_out, int out_size, void* d_ws, size_t ws_size,
                              hipStream_t stream)
{
  const float* x     = (const float*)d_in[0];
  const int*   ei    = (const int*)d_in[1];
  const int*   batch = (const int*)d_in[2];
  const float* W1    = (const float*)d_in[3];
  const float* W2    = (const float*)d_in[4];
  const float* Wfc   = (const float*)d_in[5];
  float* out = (float*)d_out;

  const int* src = ei;            // edge_index[0]
  const int* dst = ei + N_EDGES;  // edge_index[1]

  // ---- workspace layout (~36 MB) ----
  u32* gcur    = (u32*)d_ws;                        // NBKT*16 padded cursors (zeroed)
  u32* buckets = gcur + (size_t)NBKT * GSTRIDE;     // NBKT*CAP (16MB)
  u16* q1b = (u16*)(buckets + (size_t)NBKT * CAP);  // N*16 bf16 = 3.2MB
  u16* q2b = q1b + (size_t)N_NODES * QB;            // 3.2MB
  float* p1 = (float*)(q2b + (size_t)N_NODES * QB); // N*10 f32 (4MB)
  float* p2 = p1 + (size_t)N_NODES * DIM;           // 4MB
  float* h2 = p2 + (size_t)N_NODES * DIM;           // N*12 f32 (4.8MB)

  hipMemsetAsync(gcur, 0, (size_t)NBKT * GSTRIDE * sizeof(u32), stream);

  k_gemm1 <<<NBLK_N, 256, 0, stream>>>(x, W1, p1, q1b);
  k_bucket<<<NBLK_E, 256, 0, stream>>>(src, dst, gcur, buckets);
  k_lay1  <<<NBKT, 256, 0, stream>>>(gcur, buckets, p1, q1b, W2, p2, q2b);
  k_lay2  <<<NBKT, 256, 0, stream>>>(gcur, buckets, p2, q2b, h2);
  k_pool  <<<B_GRAPHS, 64, 0, stream>>>(h2, batch, Wfc, out);
}

// Round 8
// 247.122 us; speedup vs baseline: 2.5240x; 1.1440x over previous
//
#include <hip/hip_runtime.h>
#include <cstdint>

typedef unsigned int u32;
typedef unsigned short u16;

#define N_NODES 100000
#define N_EDGES 3200000
#define F_IN 128
#define DIM 10
#define QB 16            // bf16 elems per padded q row -> 32B
#define HPAD 12          // f32 h2 row stride (48B) for the pool kernel
#define B_GRAPHS 1000
#define NBLK_N 391       // ceil(N/256)
#define RNG 64           // dst nodes per fine bucket
#define NBKT 1563        // ceil(100000/64) fine buckets
#define CAP 2560         // slots/fine bucket: mean 2048 + 11 sigma
#define NCOARSE 98       // ceil(100000/1024) coarse buckets (dst>>10)
#define CAPC 34816       // slots/coarse bucket: mean 32768 + ~11 sigma (180)
#define CHUNK 8192       // edges per k_coarse block
#define NBLK_E 391       // ceil(E/CHUNK)
#define SLICES 5         // ceil(CAPC/CHUNK) slices per coarse bucket in k_split
#define GSTRIDE 16       // cursor padding: one 64B line per cursor

__device__ __forceinline__ u16 f2b(float f) {           // f32 -> bf16 (RNE)
  union { float f; u32 i; } c; c.f = f;
  u32 r = c.i + 0x7FFFu + ((c.i >> 16) & 1u);
  return (u16)(r >> 16);
}
__device__ __forceinline__ float bl(u32 u) {            // low bf16 -> f32
  union { u32 i; float f; } c; c.i = u << 16; return c.f;
}
__device__ __forceinline__ float bh(u32 u) {            // high bf16 -> f32
  union { u32 i; float f; } c; c.i = u & 0xFFFF0000u; return c.f;
}

// p1 = x @ W1[:128,:] (f32, stride 10); q1 = x @ W1[128:,:] (bf16, 32B rows)
__global__ __launch_bounds__(256) void k_gemm1(
    const float* __restrict__ x, const float* __restrict__ W,
    float* __restrict__ p1, u16* __restrict__ q1b)
{
  int i = blockIdx.x * 256 + threadIdx.x;
  if (i >= N_NODES) return;
  const float4* __restrict__ xr = (const float4*)(x + (size_t)i * F_IN);
  float ap[DIM], aq[DIM];
  #pragma unroll
  for (int j = 0; j < DIM; ++j) { ap[j] = 0.f; aq[j] = 0.f; }
  #pragma unroll 4
  for (int k4 = 0; k4 < F_IN / 4; ++k4) {
    float4 v = xr[k4];
    const float* __restrict__ w0 = W + (k4 * 4) * DIM;
    const float* __restrict__ w1 = W + (F_IN + k4 * 4) * DIM;
    #pragma unroll
    for (int j = 0; j < DIM; ++j) {
      ap[j] += v.x * w0[j] + v.y * w0[DIM + j] + v.z * w0[2 * DIM + j] + v.w * w0[3 * DIM + j];
      aq[j] += v.x * w1[j] + v.y * w1[DIM + j] + v.z * w1[2 * DIM + j] + v.w * w1[3 * DIM + j];
    }
  }
  float* pr = p1 + (size_t)i * DIM;
  #pragma unroll
  for (int j = 0; j < DIM; ++j) pr[j] = ap[j];
  u32* qr = (u32*)(q1b + (size_t)i * QB);
  uint4 v0; u32 v1;
  v0.x = (u32)f2b(aq[0]) | ((u32)f2b(aq[1]) << 16);
  v0.y = (u32)f2b(aq[2]) | ((u32)f2b(aq[3]) << 16);
  v0.z = (u32)f2b(aq[4]) | ((u32)f2b(aq[5]) << 16);
  v0.w = (u32)f2b(aq[6]) | ((u32)f2b(aq[7]) << 16);
  v1   = (u32)f2b(aq[8]) | ((u32)f2b(aq[9]) << 16);
  *(uint4*)qr = v0;
  qr[4] = v1;
}

// Pass 1: bucket edges into 98 coarse ranges (1024 dst each). Per-(block,
// coarse) segments ~84 records = ~336B contiguous -> write amp ~1.2x.
// Record: ((dst & 1023) << 17) | src
__global__ __launch_bounds__(256) void k_coarse(
    const int* __restrict__ src, const int* __restrict__ dst,
    u32* __restrict__ gcurc, u32* __restrict__ coarse)
{
  __shared__ u32 hcnt[NCOARSE];
  __shared__ u32 gbase[NCOARSE];
  int tid = threadIdx.x;
  if (tid < NCOARSE) hcnt[tid] = 0u;
  __syncthreads();
  int base = blockIdx.x * CHUNK;
  #pragma unroll
  for (int it = 0; it < CHUNK / 256; ++it) {
    int e = base + it * 256 + tid;
    if (e < N_EDGES) atomicAdd(&hcnt[(u32)dst[e] >> 10], 1u);
  }
  __syncthreads();
  if (tid < NCOARSE) {
    u32 c = hcnt[tid];
    gbase[tid] = c ? atomicAdd(&gcurc[tid * GSTRIDE], c) : 0u;
    hcnt[tid] = 0u;
  }
  __syncthreads();
  #pragma unroll
  for (int it = 0; it < CHUNK / 256; ++it) {
    int e = base + it * 256 + tid;
    if (e < N_EDGES) {
      u32 d = (u32)dst[e];
      u32 cb = d >> 10;
      u32 ofs = atomicAdd(&hcnt[cb], 1u);
      u32 p = gbase[cb] + ofs;
      if (p < CAPC)   // statistically impossible; memory-safety only
        coarse[(size_t)cb * CAPC + p] = ((d & 1023u) << 17) | (u32)src[e];
    }
  }
}

// Pass 2: split one 8192-record slice of a coarse bucket into its 16 fine
// buckets. Per-(block,fine) segments ~512 records = 2KB contiguous.
// Fine record = coarse record & 0x7FFFFF (dl6 in bits 17..22).
__global__ __launch_bounds__(256) void k_split(
    const u32* __restrict__ gcurc, const u32* __restrict__ coarse,
    u32* __restrict__ gcur, u32* __restrict__ buckets)
{
  int c = blockIdx.x, sl = blockIdx.y;
  int n = min((int)gcurc[c * GSTRIDE], CAPC);
  int beg = sl * CHUNK, end = min(beg + CHUNK, n);
  if (beg >= end) return;           // uniform across block
  __shared__ u32 lrec[CHUNK];       // 32 KB
  __shared__ u32 hist[16];
  __shared__ u32 base16[16];
  int tid = threadIdx.x;
  if (tid < 16) hist[tid] = 0u;
  __syncthreads();
  const u32* __restrict__ rc = coarse + (size_t)c * CAPC;
  int cnt = end - beg;
  for (int r = tid; r < cnt; r += 256) {
    u32 v = rc[beg + r];
    lrec[r] = v;
    atomicAdd(&hist[(v >> 23) & 15u], 1u);
  }
  __syncthreads();
  if (tid < 16) {
    u32 h = hist[tid];
    int fb = (c << 4) + tid;        // == dst>>6, always < NBKT for real dst
    base16[tid] = h ? atomicAdd(&gcur[fb * GSTRIDE], h) : 0u;
    hist[tid] = 0u;
  }
  __syncthreads();
  for (int r = tid; r < cnt; r += 256) {
    u32 v = lrec[r];
    u32 f = (v >> 23) & 15u;
    u32 ofs = atomicAdd(&hist[f], 1u);
    u32 p = base16[f] + ofs;
    u32 fb = (c << 4) + f;
    if (p < CAP)                    // memory-safety only
      buckets[(size_t)fb * CAP + p] = v & 0x7FFFFFu;
  }
}

// Shared gather machinery: counting-sort records by dl in LDS, then 4 lanes
// per node reduce the contiguous segment in registers (no f32 atomics).
#define SORT_AND_GATHER(QSRC)                                                 \
  int tid = threadIdx.x;                                                      \
  __shared__ u32 lrec[CAP];                                                   \
  __shared__ u32 srt[CAP];                                                    \
  __shared__ u32 hist[RNG];                                                   \
  __shared__ u32 segst[RNG + 1];                                              \
  __shared__ u32 rank[RNG];                                                   \
  if (tid < RNG) { hist[tid] = 0u; rank[tid] = 0u; }                          \
  __syncthreads();                                                            \
  int b = blockIdx.x;                                                         \
  int n = min((int)gcur[b * GSTRIDE], CAP);                                   \
  const u32* __restrict__ rec = buckets + (size_t)b * CAP;                    \
  for (int r = tid; r < n; r += 256) {                                        \
    u32 v = rec[r];                                                           \
    lrec[r] = v;                                                              \
    atomicAdd(&hist[v >> 17], 1u);                                            \
  }                                                                           \
  __syncthreads();                                                            \
  if (tid < RNG) {                                                            \
    u32 h = hist[tid];                                                        \
    u32 v = h;                                                                \
    for (int off = 1; off < RNG; off <<= 1) {                                 \
      u32 t = __shfl_up(v, off, 64);                                          \
      if (tid >= off) v += t;                                                 \
    }                                                                         \
    segst[tid] = v - h;                                                       \
    if (tid == RNG - 1) segst[RNG] = v;                                       \
  }                                                                           \
  __syncthreads();                                                            \
  for (int r = tid; r < n; r += 256) {                                        \
    u32 v = lrec[r];                                                          \
    u32 dl = v >> 17;                                                         \
    u32 pos = segst[dl] + atomicAdd(&rank[dl], 1u);                           \
    srt[pos] = v & 0x1FFFFu;                                                  \
  }                                                                           \
  __syncthreads();                                                            \
  int g = tid >> 2;                                                           \
  int l = tid & 3;                                                            \
  int st = (int)segst[g], en = (int)segst[g + 1];                             \
  float s[DIM];                                                               \
  _Pragma("unroll")                                                           \
  for (int j = 0; j < DIM; ++j) s[j] = 0.f;                                   \
  int k = st + l;                                                             \
  for (; k + 4 < en; k += 8) {                                                \
    int s0 = (int)srt[k], s1 = (int)srt[k + 4];                               \
    const u32* __restrict__ q0 = (const u32*)(QSRC + (size_t)s0 * QB);        \
    const u32* __restrict__ q1 = (const u32*)(QSRC + (size_t)s1 * QB);        \
    uint4 A0 = *(const uint4*)q0; u32 B0 = q0[4];                             \
    uint4 A1 = *(const uint4*)q1; u32 B1 = q1[4];                             \
    s[0] += bl(A0.x) + bl(A1.x); s[1] += bh(A0.x) + bh(A1.x);                 \
    s[2] += bl(A0.y) + bl(A1.y); s[3] += bh(A0.y) + bh(A1.y);                 \
    s[4] += bl(A0.z) + bl(A1.z); s[5] += bh(A0.z) + bh(A1.z);                 \
    s[6] += bl(A0.w) + bl(A1.w); s[7] += bh(A0.w) + bh(A1.w);                 \
    s[8] += bl(B0) + bl(B1);     s[9] += bh(B0) + bh(B1);                     \
  }                                                                           \
  if (k < en) {                                                               \
    int s0 = (int)srt[k];                                                     \
    const u32* __restrict__ q0 = (const u32*)(QSRC + (size_t)s0 * QB);        \
    uint4 A0 = *(const uint4*)q0; u32 B0 = q0[4];                             \
    s[0] += bl(A0.x); s[1] += bh(A0.x);                                       \
    s[2] += bl(A0.y); s[3] += bh(A0.y);                                       \
    s[4] += bl(A0.z); s[5] += bh(A0.z);                                       \
    s[6] += bl(A0.w); s[7] += bh(A0.w);                                       \
    s[8] += bl(B0);   s[9] += bh(B0);                                         \
  }                                                                           \
  _Pragma("unroll")                                                           \
  for (int m = 1; m < 4; m <<= 1) {                                           \
    _Pragma("unroll")                                                         \
    for (int j = 0; j < DIM; ++j) s[j] += __shfl_xor(s[j], m, 4);             \
  }

// Layer 1: sorted gather + epilogue h = relu(p1+mean), (p2,q2) = h @ W2.
__global__ __launch_bounds__(256) void k_lay1(
    const u32* __restrict__ gcur, const u32* __restrict__ buckets,
    const float* __restrict__ p1, const u16* __restrict__ q1b,
    const float* __restrict__ W2,
    float* __restrict__ p2, u16* __restrict__ q2b)
{
  __shared__ float w[2 * DIM * DIM];
  for (int t = threadIdx.x; t < 2 * DIM * DIM; t += 256) w[t] = W2[t];
  SORT_AND_GATHER(q1b)
  if (l == 0) {
    int i = b * RNG + g;
    if (i < N_NODES) {
      float inv = 1.0f / fmaxf((float)(en - st), 1.0f);
      const float* __restrict__ pr = p1 + (size_t)i * DIM;
      float h[DIM];
      #pragma unroll
      for (int j = 0; j < DIM; ++j) h[j] = fmaxf(pr[j] + s[j] * inv, 0.0f);
      float aa[DIM], bb[DIM];
      #pragma unroll
      for (int j = 0; j < DIM; ++j) {
        float t0 = 0.f, t1 = 0.f;
        #pragma unroll
        for (int kk = 0; kk < DIM; ++kk) {
          t0 += h[kk] * w[kk * DIM + j];
          t1 += h[kk] * w[(DIM + kk) * DIM + j];
        }
        aa[j] = t0; bb[j] = t1;
      }
      float* po = p2 + (size_t)i * DIM;
      #pragma unroll
      for (int j = 0; j < DIM; ++j) po[j] = aa[j];
      u32* qo = (u32*)(q2b + (size_t)i * QB);
      uint4 v0; u32 v1;
      v0.x = (u32)f2b(bb[0]) | ((u32)f2b(bb[1]) << 16);
      v0.y = (u32)f2b(bb[2]) | ((u32)f2b(bb[3]) << 16);
      v0.z = (u32)f2b(bb[4]) | ((u32)f2b(bb[5]) << 16);
      v0.w = (u32)f2b(bb[6]) | ((u32)f2b(bb[7]) << 16);
      v1   = (u32)f2b(bb[8]) | ((u32)f2b(bb[9]) << 16);
      *(uint4*)qo = v0;
      qo[4] = v1;
    }
  }
}

// Layer 2: sorted gather + epilogue h2 = p2 + mean (f32, stride 12).
__global__ __launch_bounds__(256) void k_lay2(
    const u32* __restrict__ gcur, const u32* __restrict__ buckets,
    const float* __restrict__ p2, const u16* __restrict__ q2b,
    float* __restrict__ h2)
{
  SORT_AND_GATHER(q2b)
  if (l == 0) {
    int i = b * RNG + g;
    if (i < N_NODES) {
      float inv = 1.0f / fmaxf((float)(en - st), 1.0f);
      const float* __restrict__ pr = p2 + (size_t)i * DIM;
      float* ho = h2 + (size_t)i * HPAD;
      #pragma unroll
      for (int j = 0; j < DIM; ++j) ho[j] = pr[j] + s[j] * inv;
    }
  }
}

// one wave per graph: binary-search node range in sorted batch, mean-pool,
// dot with Wfc, sigmoid -> out[b]. Zero atomics.
__global__ __launch_bounds__(64) void k_pool(
    const float* __restrict__ h2, const int* __restrict__ batch,
    const float* __restrict__ Wfc, float* __restrict__ out)
{
  int b = blockIdx.x;
  int lo = 0, hi = N_NODES;
  while (lo < hi) { int m = (lo + hi) >> 1; if (batch[m] < b) lo = m + 1; else hi = m; }
  int start = lo;
  hi = N_NODES;
  while (lo < hi) { int m = (lo + hi) >> 1; if (batch[m] < b + 1) lo = m + 1; else hi = m; }
  int end = lo;
  float sum[DIM];
  #pragma unroll
  for (int j = 0; j < DIM; ++j) sum[j] = 0.f;
  for (int r = start + (int)threadIdx.x; r < end; r += 64) {
    const float4* __restrict__ p = (const float4*)(h2 + (size_t)r * HPAD);
    float4 r0 = p[0], r1 = p[1];
    float2 r2 = *(const float2*)(h2 + (size_t)r * HPAD + 8);
    sum[0] += r0.x; sum[1] += r0.y; sum[2] += r0.z; sum[3] += r0.w;
    sum[4] += r1.x; sum[5] += r1.y; sum[6] += r1.z; sum[7] += r1.w;
    sum[8] += r2.x; sum[9] += r2.y;
  }
  #pragma unroll
  for (int m = 1; m < 64; m <<= 1) {
    #pragma unroll
    for (int j = 0; j < DIM; ++j) sum[j] += __shfl_xor(sum[j], m, 64);
  }
  if (threadIdx.x == 0) {
    float inv = 1.0f / fmaxf((float)(end - start), 1.0f);
    float acc = 0.f;
    #pragma unroll
    for (int j = 0; j < DIM; ++j) acc += sum[j] * inv * Wfc[j];
    out[b] = 1.0f / (1.0f + expf(-acc));
  }
}

extern "C" void kernel_launch(void* const* d_in, const int* in_sizes, int n_in,
                              void* d_out, int out_size, void* d_ws, size_t ws_size,
                              hipStream_t stream)
{
  const float* x     = (const float*)d_in[0];
  const int*   ei    = (const int*)d_in[1];
  const int*   batch = (const int*)d_in[2];
  const float* W1    = (const float*)d_in[3];
  const float* W2    = (const float*)d_in[4];
  const float* Wfc   = (const float*)d_in[5];
  float* out = (float*)d_out;

  const int* src = ei;            // edge_index[0]
  const int* dst = ei + N_EDGES;  // edge_index[1]

  // ---- workspace layout (~37 MB). coarse region is dead after k_split,
  //      so q1b/p1/h2 alias into it (k_gemm1 runs after k_split). ----
  u32* gcurc   = (u32*)d_ws;                          // 98*16, pad 2048 (zeroed)
  u32* gcur    = gcurc + 2048;                        // 1563*16 = 25008 (zeroed)
  u32* buckets = gcur + (size_t)NBKT * GSTRIDE;       // 1563*2560 = 16.0 MB
  u32* coarse  = buckets + (size_t)NBKT * CAP;        // 98*34816 = 13.65 MB
  u16* q1b = (u16*)coarse;                            // N*16 bf16 (3.2MB, aliased)
  float* p1 = (float*)(coarse + 800000);              // N*10 f32 (4MB, aliased)
  float* h2 = (float*)(coarse + 1800000);             // N*12 f32 (4.8MB, aliased)
  u32* after = coarse + (size_t)NCOARSE * CAPC;
  u16* q2b = (u16*)after;                             // N*16 bf16 (3.2MB)
  float* p2 = (float*)(after + 800000);               // N*10 f32 (4MB)

  hipMemsetAsync(d_ws, 0, (2048 + (size_t)NBKT * GSTRIDE) * sizeof(u32), stream);

  k_coarse<<<NBLK_E, 256, 0, stream>>>(src, dst, gcurc, coarse);
  k_split <<<dim3(NCOARSE, SLICES), 256, 0, stream>>>(gcurc, coarse, gcur, buckets);
  k_gemm1 <<<NBLK_N, 256, 0, stream>>>(x, W1, p1, q1b);   // overwrites coarse (dead)
  k_lay1  <<<NBKT, 256, 0, stream>>>(gcur, buckets, p1, q1b, W2, p2, q2b);
  k_lay2  <<<NBKT, 256, 0, stream>>>(gcur, buckets, p2, q2b, h2);
  k_pool  <<<B_GRAPHS, 64, 0, stream>>>(h2, batch, Wfc, out);
}